// Round 17
// baseline (116.285 us; speedup 1.0000x reference)
//
#include <hip/hip_runtime.h>
#include <hip/hip_bf16.h>

// ConvexWidthUpsampler R17: R15 core + 128-thread blocks for occupancy.
//  - BT=128 (2 waves): LDS 14368 B/block -> 11 blocks/CU -> 22 waves/CU
//  - work unit = 128 px (quarter image row; scalar row addressing)
//  - interior waves: clamp-free scalar dword x-loads (no vector widening!)
//  - stores: 3x dword (R16's float3 store caused RMW write amplification)
// 112B self-swizzling rows, weak memory-clobber fences, z in registers
// (permuted-M2 trick). B=16,C=1,H=512,W=512,up=(1,3). Output f32.

#define BB 16
#define HH 512
#define WW 512
#define HID 32
#define NM 27
#define LOG2E 1.44269504088896340736f
#define NT2 32768    // total 128-px work units
#define NBLK2 2816   // 11 blocks/CU x 256 CU
#define ROWB 112
#define ZOFF (64 * ROWB)   // 7168: per-wave broadcast-zero block

typedef short bf16x8 __attribute__((ext_vector_type(8)));
typedef float f32x4  __attribute__((ext_vector_type(4)));
typedef unsigned int u32;
typedef u32 u32x4 __attribute__((ext_vector_type(4)));

__device__ __forceinline__ u32 pk2(float a, float b) {
    union { __hip_bfloat162 h2; u32 u; } cv;
    cv.h2 = __float22bfloat162_rn(make_float2(a, b));
    return cv.u;
}

// Compiler memory fence: forbids CSE/reordering of LDS ops across stages
// (TBAA guard for type-punned same-address accesses, the R5 bug class).
// No sched_barrier: VALU/MFMA float freely for latency hiding.
__device__ __forceinline__ void lds_fence() {
    asm volatile("" ::: "memory");
}

// 3x3 load. ht = 128-px unit index: wcol = (ht&3)*128 + tid (tid 0..127),
// hrow = (ht>>2)&511, bidx = ht>>11 -- row logic is wave-uniform scalar.
// Interior waves: 9 plain dword loads (no clamps). Boundary: clamped+cndmask.
__device__ __forceinline__ void load_xv(const float* __restrict__ x, int ht,
                                        int tid, float xv[9]) {
    const int wcol = (ht & 3) * 128 + tid;
    const int hrow = (ht >> 2) & (HH - 1);
    const int bidx = ht >> 11;
    const float* xb = x + (size_t)bidx * (HH * WW);
    const int w0 = (ht & 3) * 128 + (tid & 64);   // wave-uniform
    if (w0 != 0 && w0 != 448 && hrow != 0 && hrow != (HH - 1)) {
        const float* xp = xb + hrow * WW + wcol;
#pragma unroll
        for (int ki = 0; ki < 3; ++ki)
#pragma unroll
            for (int kj = 0; kj < 3; ++kj)
                xv[ki * 3 + kj] = xp[(ki - 1) * WW + (kj - 1)];
    } else {
        int wx[3]; bool wok[3];
#pragma unroll
        for (int i = 0; i < 3; ++i) {
            const int w = wcol + i - 1;
            wok[i] = (unsigned)w < (unsigned)WW;
            wx[i]  = w < 0 ? 0 : (w > WW - 1 ? WW - 1 : w);
        }
#pragma unroll
        for (int ki = 0; ki < 3; ++ki) {
            const int h = hrow + ki - 1;                   // scalar
            const bool hok = (unsigned)h < (unsigned)HH;   // scalar
            const int hy = h < 0 ? 0 : (h > HH - 1 ? HH - 1 : h);
            const float* rowp = xb + hy * WW;
#pragma unroll
            for (int kj = 0; kj < 3; ++kj) {
                const float v = rowp[wx[kj]];
                xv[ki * 3 + kj] = (hok && wok[kj]) ? v : 0.0f;
            }
        }
    }
}

// ws bf16 layout (hi-only, 3072 elems = 6 KB):
//   [0   ..1023] B2_32 [32 n][32 k]: k<9 M1[n][k], k==9 bias'[n], else 0 (xlog2e)
//   [1024..2047] M2p   [32 n][32 k]: M2[n][pi(k)] (xlog2e), n>=27 -> 0
//   [2048..3071] B1    [32 n][32 k]: k<9 w1[n][k], k==9 b1[n], else 0
__global__ void prep_B(const float* __restrict__ w1, const float* __restrict__ b1,
                       const float* __restrict__ alpha, const float* __restrict__ w2,
                       const float* __restrict__ b2, __hip_bfloat16* __restrict__ ws) {
    const int i = blockIdx.x * 256 + threadIdx.x;
    if (i >= 3072) return;
    const int sec = i >> 10;
    const int r   = i & 1023;
    const int n   = r >> 5, k = r & 31;
    float v = 0.0f;
    if (sec == 0) {
        if (n < NM) {
            if (k < 9) {
                for (int c = 0; c < HID; ++c)
                    v += w2[n * HID + c] * (0.5f * (1.0f + alpha[c])) * w1[c * 9 + k];
            } else if (k == 9) {
                v = b2[n];
                for (int c = 0; c < HID; ++c)
                    v += w2[n * HID + c] * (0.5f * (1.0f + alpha[c])) * b1[c];
            }
        }
        v *= LOG2E;
    } else if (sec == 1) {
        if (n < NM) {
            const int c = ((k & 4) ? 16 : 0) + (k >> 3) * 4 + (k & 3);  // pi(k)
            v = w2[n * HID + c] * (0.5f * (1.0f - alpha[c])) * LOG2E;
        }
    } else {
        v = (k < 9) ? w1[n * 9 + k] : (k == 9 ? b1[n] : 0.0f);
    }
    ws[i] = __float2bfloat16(v);
}

__global__ __launch_bounds__(128, 6) void convex_upsample_mfma13(
    const float* __restrict__ x,            // [16,1,512,512]
    const __hip_bfloat16* __restrict__ ws,  // prep output
    float* __restrict__ out)                // [16,1,512,1536]
{
    __shared__ char lds_raw[2][ZOFF + 16];  // 2 x 7184 = 14368 B -> 11 blocks/CU

    const int tid  = threadIdx.x;
    const int wv   = tid >> 6;
    const int lane = tid & 63;
    const int l16  = lane & 15;
    const int lq   = lane >> 4;
    char* wbase = lds_raw[wv];

    // persistent weight fragments (hi only): lane row n = nt*16+l16, k = lq*8+i
    bf16x8 Bf2[2], M2p[2], Bf1[2];
#pragma unroll
    for (int nt = 0; nt < 2; ++nt) {
        const int ro = (nt * 16 + l16) * 32 + lq * 8;
        Bf2[nt] = *(const bf16x8*)(ws + ro);
        M2p[nt] = *(const bf16x8*)(ws + 1024 + ro);
        Bf1[nt] = *(const bf16x8*)(ws + 2048 + ro);
    }

    // broadcast-zero block (idempotent per-wave write; read by lq>=2 a0 loads)
    *(u32x4*)(wbase + ZOFF) = (u32x4){0u, 0u, 0u, 0u};

    int tb = blockIdx.x;
    int ob = (blockIdx.x * 128 + tid) * 3;   // running output offset (fits i32)
    float xv[9];
    load_xv(x, tb, tid, xv);

    while (tb < NT2) {
        const int tn  = tb + NBLK2;
        const int tpf = (tn < NT2) ? tn : 0;
        float xn[9];
        load_xv(x, tpf, tid, xn);   // prefetch next unit during this compute

        // ---- init my row bytes 0..31: k0..8=xv, k9=1, k10..15=0 ----
        char* myrow = wbase + lane * ROWB;
        *(u32x4*)(myrow)      = (u32x4){pk2(xv[0], xv[1]), pk2(xv[2], xv[3]),
                                        pk2(xv[4], xv[5]), pk2(xv[6], xv[7])};
        *(u32x4*)(myrow + 16) = (u32x4){pk2(xv[8], 1.0f), 0u, 0u, 0u};

        lds_fence();   // init writes -> cross-lane a0 reads

        // ---- hoisted a0 reads; lq>=2 lanes read the broadcast-zero block ----
        bf16x8 a0[4];
#pragma unroll
        for (int mt = 0; mt < 4; ++mt) {
            const char* ab = wbase + (mt * 16 + l16) * ROWB;
            const char* aptr = (lq < 2) ? (ab + lq * 16) : (wbase + ZOFF);
            a0[mt] = *(const bf16x8*)aptr;
        }

        lds_fence();   // a0 reads -> scatters below (TBAA/reorder guard)

        // ---- per mt: z in-register -> logits -> scatter ----
#pragma unroll
        for (int mt = 0; mt < 4; ++mt) {
            char* ab = wbase + (mt * 16 + l16) * ROWB;
            // round 1: z[ch][px]; lane(l16,lq) gets ch = {lq*4+r, 16+lq*4+r}, px = l16
            f32x4 z0 = {0.f, 0.f, 0.f, 0.f}, z1 = {0.f, 0.f, 0.f, 0.f};
            z0 = __builtin_amdgcn_mfma_f32_16x16x32_bf16(Bf1[0], a0[mt], z0, 0, 0, 0);
            z1 = __builtin_amdgcn_mfma_f32_16x16x32_bf16(Bf1[1], a0[mt], z1, 0, 0, 0);
            // pack |z| as permuted B-operand fragment (k = lq*8+i -> ch pi(k))
            union { u32 u[4]; bf16x8 h; } zf;
            zf.u[0] = pk2(fabsf(z0[0]), fabsf(z0[1]));
            zf.u[1] = pk2(fabsf(z0[2]), fabsf(z0[3]));
            zf.u[2] = pk2(fabsf(z1[0]), fabsf(z1[1]));
            zf.u[3] = pk2(fabsf(z1[2]), fabsf(z1[3]));
            // round 2: logits m[n][px] = M2p*|z| + B2*a0
            f32x4 c0 = {0.f, 0.f, 0.f, 0.f}, c1 = {0.f, 0.f, 0.f, 0.f};
            c0 = __builtin_amdgcn_mfma_f32_16x16x32_bf16(M2p[0], zf.h,   c0, 0, 0, 0);
            c0 = __builtin_amdgcn_mfma_f32_16x16x32_bf16(Bf2[0], a0[mt], c0, 0, 0, 0);
            c1 = __builtin_amdgcn_mfma_f32_16x16x32_bf16(M2p[1], zf.h,   c1, 0, 0, 0);
            c1 = __builtin_amdgcn_mfma_f32_16x16x32_bf16(Bf2[1], a0[mt], c1, 0, 0, 0);
            // scatter for pixel mt*16+l16: lane(l16,lq) holds
            //   c0: n = lq*4..+3      -> bytes 48 + lq*16 (48..111)
            //   c1: n = 16+lq*4..+3   -> bytes lq*16 (0..47), lq==3 (n>=28) dropped
            *(f32x4*)(ab + 48 + lq * 16) = c0;
            if (lq < 3) *(f32x4*)(ab + lq * 16) = c1;
        }

        lds_fence();   // scatters -> readback

        // ---- readback 27 logits: n0..15 @ bytes 48..111, n16..26 @ 0..43 ----
        f32x4 mv[7];
#pragma unroll
        for (int q = 0; q < 4; ++q)
            mv[q] = *(const f32x4*)(myrow + 48 + q * 16);
#pragma unroll
        for (int q = 0; q < 3; ++q)
            mv[4 + q] = *(const f32x4*)(myrow + q * 16);

        // ---- softmax (base-2, pre-scaled, no max-sub) + combine + store ----
#pragma unroll
        for (int v = 0; v < 3; ++v) {
            float ssum = 0.0f, acc = 0.0f;
#pragma unroll
            for (int k = 0; k < 9; ++k) {
                const int j = k * 3 + v;
                const float lg = (j < 16) ? mv[j >> 2][j & 3]
                                          : mv[4 + ((j - 16) >> 2)][(j - 16) & 3];
                const float e = __builtin_amdgcn_exp2f(lg);
                ssum += e;
                acc = fmaf(xv[k], e, acc);
            }
            out[ob + v] = acc * __builtin_amdgcn_rcpf(ssum);
        }

        lds_fence();   // readback -> next iteration's init writes

        tb = tn;
        ob += NBLK2 * 128 * 3;
#pragma unroll
        for (int k = 0; k < 9; ++k) xv[k] = xn[k];
    }
}

extern "C" void kernel_launch(void* const* d_in, const int* in_sizes, int n_in,
                              void* d_out, int out_size, void* d_ws, size_t ws_size,
                              hipStream_t stream) {
    // setup_inputs order: x, target_h, target_w, w1, b1, alpha, w2, b2
    const float* x     = (const float*)d_in[0];
    const float* w1    = (const float*)d_in[3];
    const float* b1    = (const float*)d_in[4];
    const float* alpha = (const float*)d_in[5];
    const float* w2    = (const float*)d_in[6];
    const float* b2    = (const float*)d_in[7];
    float* out = (float*)d_out;
    __hip_bfloat16* ws = (__hip_bfloat16*)d_ws;   // 3072 bf16 = 6 KB

    hipLaunchKernelGGL(prep_B, dim3(12), dim3(256), 0, stream, w1, b1, alpha, w2, b2, ws);
    hipLaunchKernelGGL(convex_upsample_mfma13, dim3(NBLK2), dim3(128), 0, stream,
                       x, ws, out);
}

// Round 18
// 115.599 us; speedup vs baseline: 1.0059x; 1.0059x over previous
//
#include <hip/hip_runtime.h>
#include <hip/hip_bf16.h>

// ConvexWidthUpsampler R18: R15 core + bf16 logits -> 80B rows -> 7 blocks/CU.
//  - row = 80 B (5x16B): stride 20 banks mod 32, period-8 self-rotation
//    (same conflict-free family as the measured-good 112B rows)
//  - logits stored as bf16 (cvt_pk packed), scatter = ds_write_b64 pairs,
//    readback = 4x ds_read_b128, softmax unpacks with shift/and
//  - LDS 20544 B/block -> 7 blocks/CU = 28 waves/CU ceiling (87.5%)
//  - NBLK 1792 = 7 x 256 (single resident cohort), 9-10 tiles/block
// Weak memory-clobber fences, z in registers (permuted-M2), scalar stores.
// B=16,C=1,H=512,W=512,up=(1,3). Output [16,1,512,1536] f32.

#define BB 16
#define HH 512
#define WW 512
#define HID 32
#define NM 27
#define LOG2E 1.44269504088896340736f
#define NT 16384
#define NBLK 1792
#define ROWB 80
#define ZOFF (64 * ROWB)   // 5120: per-wave broadcast-zero block

typedef short bf16x8 __attribute__((ext_vector_type(8)));
typedef float f32x4  __attribute__((ext_vector_type(4)));
typedef unsigned int u32;
typedef u32 u32x4 __attribute__((ext_vector_type(4)));
typedef u32 u32x2 __attribute__((ext_vector_type(2)));

__device__ __forceinline__ u32 pk2(float a, float b) {
    union { __hip_bfloat162 h2; u32 u; } cv;
    cv.h2 = __float22bfloat162_rn(make_float2(a, b));
    return cv.u;
}

// Compiler memory fence: forbids CSE/reordering of LDS ops across stages
// (TBAA guard for type-punned same-address accesses, the R5 bug class).
// No sched_barrier: VALU/MFMA float freely for latency hiding.
__device__ __forceinline__ void lds_fence() {
    asm volatile("" ::: "memory");
}

// 3x3 load with wave-uniform row logic (R15-proven): block covers half of
// one image row, so hrow/bidx/row-masks are scalar.
__device__ __forceinline__ void load_xv(const float* __restrict__ x, int tile,
                                        int tid, float xv[9]) {
    const int wcol = (tile & 1) * 256 + tid;       // lane-varying
    const int hrow = (tile >> 1) & (HH - 1);       // scalar
    const int bidx = tile >> 10;                   // scalar
    const float* xb = x + (size_t)bidx * (HH * WW);
    int wx[3]; bool wok[3];
#pragma unroll
    for (int i = 0; i < 3; ++i) {
        const int w = wcol + i - 1;
        wok[i] = (unsigned)w < (unsigned)WW;
        wx[i]  = w < 0 ? 0 : (w > WW - 1 ? WW - 1 : w);
    }
#pragma unroll
    for (int ki = 0; ki < 3; ++ki) {
        const int h = hrow + ki - 1;                       // scalar
        const bool hok = (unsigned)h < (unsigned)HH;       // scalar
        const int hy = h < 0 ? 0 : (h > HH - 1 ? HH - 1 : h);
        const float* rowp = xb + hy * WW;                  // scalar base
#pragma unroll
        for (int kj = 0; kj < 3; ++kj) {
            const float v = rowp[wx[kj]];
            xv[ki * 3 + kj] = (hok && wok[kj]) ? v : 0.0f;
        }
    }
}

// ws bf16 layout (hi-only, 3072 elems = 6 KB):
//   [0   ..1023] B2_32 [32 n][32 k]: k<9 M1[n][k], k==9 bias'[n], else 0 (xlog2e)
//   [1024..2047] M2p   [32 n][32 k]: M2[n][pi(k)] (xlog2e), n>=27 -> 0
//   [2048..3071] B1    [32 n][32 k]: k<9 w1[n][k], k==9 b1[n], else 0
__global__ void prep_B(const float* __restrict__ w1, const float* __restrict__ b1,
                       const float* __restrict__ alpha, const float* __restrict__ w2,
                       const float* __restrict__ b2, __hip_bfloat16* __restrict__ ws) {
    const int i = blockIdx.x * 256 + threadIdx.x;
    if (i >= 3072) return;
    const int sec = i >> 10;
    const int r   = i & 1023;
    const int n   = r >> 5, k = r & 31;
    float v = 0.0f;
    if (sec == 0) {
        if (n < NM) {
            if (k < 9) {
                for (int c = 0; c < HID; ++c)
                    v += w2[n * HID + c] * (0.5f * (1.0f + alpha[c])) * w1[c * 9 + k];
            } else if (k == 9) {
                v = b2[n];
                for (int c = 0; c < HID; ++c)
                    v += w2[n * HID + c] * (0.5f * (1.0f + alpha[c])) * b1[c];
            }
        }
        v *= LOG2E;
    } else if (sec == 1) {
        if (n < NM) {
            const int c = ((k & 4) ? 16 : 0) + (k >> 3) * 4 + (k & 3);  // pi(k)
            v = w2[n * HID + c] * (0.5f * (1.0f - alpha[c])) * LOG2E;
        }
    } else {
        v = (k < 9) ? w1[n * 9 + k] : (k == 9 ? b1[n] : 0.0f);
    }
    ws[i] = __float2bfloat16(v);
}

__global__ __launch_bounds__(256, 7) void convex_upsample_mfma14(
    const float* __restrict__ x,            // [16,1,512,512]
    const __hip_bfloat16* __restrict__ ws,  // prep output
    float* __restrict__ out)                // [16,1,512,1536]
{
    __shared__ char lds_raw[4][ZOFF + 16];  // 4 x 5136 = 20544 B -> 7 blocks/CU

    const int tid  = threadIdx.x;
    const int wv   = tid >> 6;
    const int lane = tid & 63;
    const int l16  = lane & 15;
    const int lq   = lane >> 4;
    char* wbase = lds_raw[wv];

    // persistent weight fragments (hi only): lane row n = nt*16+l16, k = lq*8+i
    bf16x8 Bf2[2], M2p[2], Bf1[2];
#pragma unroll
    for (int nt = 0; nt < 2; ++nt) {
        const int ro = (nt * 16 + l16) * 32 + lq * 8;
        Bf2[nt] = *(const bf16x8*)(ws + ro);
        M2p[nt] = *(const bf16x8*)(ws + 1024 + ro);
        Bf1[nt] = *(const bf16x8*)(ws + 2048 + ro);
    }

    // broadcast-zero block (idempotent per-wave write; read by lq>=2 a0 loads)
    *(u32x4*)(wbase + ZOFF) = (u32x4){0u, 0u, 0u, 0u};

    int tb = blockIdx.x;
    float xv[9];
    load_xv(x, tb, tid, xv);

    while (tb < NT) {
        const int tn  = tb + NBLK;
        const int tpf = (tn < NT) ? tn : 0;
        float xn[9];
        load_xv(x, tpf, tid, xn);   // prefetch next tile during this compute

        // ---- init my row bytes 0..31: k0..8=xv, k9=1, k10..15=0 ----
        char* myrow = wbase + lane * ROWB;
        *(u32x4*)(myrow)      = (u32x4){pk2(xv[0], xv[1]), pk2(xv[2], xv[3]),
                                        pk2(xv[4], xv[5]), pk2(xv[6], xv[7])};
        *(u32x4*)(myrow + 16) = (u32x4){pk2(xv[8], 1.0f), 0u, 0u, 0u};

        lds_fence();   // init writes -> cross-lane a0 reads

        // ---- hoisted a0 reads; lq>=2 lanes read the broadcast-zero block ----
        bf16x8 a0[4];
#pragma unroll
        for (int mt = 0; mt < 4; ++mt) {
            const char* ab = wbase + (mt * 16 + l16) * ROWB;
            const char* aptr = (lq < 2) ? (ab + lq * 16) : (wbase + ZOFF);
            a0[mt] = *(const bf16x8*)aptr;
        }

        lds_fence();   // a0 reads -> scatters below (TBAA/reorder guard)

        // ---- per mt: z in-register -> logits -> bf16 scatter ----
#pragma unroll
        for (int mt = 0; mt < 4; ++mt) {
            char* ab = wbase + (mt * 16 + l16) * ROWB;
            // round 1: z[ch][px]; lane(l16,lq) gets ch = {lq*4+r, 16+lq*4+r}, px = l16
            f32x4 z0 = {0.f, 0.f, 0.f, 0.f}, z1 = {0.f, 0.f, 0.f, 0.f};
            z0 = __builtin_amdgcn_mfma_f32_16x16x32_bf16(Bf1[0], a0[mt], z0, 0, 0, 0);
            z1 = __builtin_amdgcn_mfma_f32_16x16x32_bf16(Bf1[1], a0[mt], z1, 0, 0, 0);
            // pack |z| as permuted B-operand fragment (k = lq*8+i -> ch pi(k))
            union { u32 u[4]; bf16x8 h; } zf;
            zf.u[0] = pk2(fabsf(z0[0]), fabsf(z0[1]));
            zf.u[1] = pk2(fabsf(z0[2]), fabsf(z0[3]));
            zf.u[2] = pk2(fabsf(z1[0]), fabsf(z1[1]));
            zf.u[3] = pk2(fabsf(z1[2]), fabsf(z1[3]));
            // round 2: logits m[n][px] = M2p*|z| + B2*a0
            f32x4 c0 = {0.f, 0.f, 0.f, 0.f}, c1 = {0.f, 0.f, 0.f, 0.f};
            c0 = __builtin_amdgcn_mfma_f32_16x16x32_bf16(M2p[0], zf.h,   c0, 0, 0, 0);
            c0 = __builtin_amdgcn_mfma_f32_16x16x32_bf16(Bf2[0], a0[mt], c0, 0, 0, 0);
            c1 = __builtin_amdgcn_mfma_f32_16x16x32_bf16(M2p[1], zf.h,   c1, 0, 0, 0);
            c1 = __builtin_amdgcn_mfma_f32_16x16x32_bf16(Bf2[1], a0[mt], c1, 0, 0, 0);
            // bf16 scatter for pixel mt*16+l16 (logit n at byte 2n):
            //   c0: n = lq*4..+3     -> bytes 8*lq      (0..31)
            //   c1: n = 16+lq*4..+3  -> bytes 32 + 8*lq (32..55), lq==3 dropped
            *(u32x2*)(ab + 8 * lq) = (u32x2){pk2(c0[0], c0[1]), pk2(c0[2], c0[3])};
            if (lq < 3)
                *(u32x2*)(ab + 32 + 8 * lq) = (u32x2){pk2(c1[0], c1[1]), pk2(c1[2], c1[3])};
        }

        lds_fence();   // scatters -> readback

        // ---- readback 27 bf16 logits (bytes 0..53) as 16 u32 words ----
        u32 mw[16];
#pragma unroll
        for (int q = 0; q < 4; ++q) {
            const u32x4 t = *(const u32x4*)(myrow + q * 16);
            mw[4 * q + 0] = t[0]; mw[4 * q + 1] = t[1];
            mw[4 * q + 2] = t[2]; mw[4 * q + 3] = t[3];
        }

        // ---- softmax (base-2, pre-scaled, no max-sub) + combine + store ----
        const int p = tb * 256 + tid;
        const size_t ob = (size_t)p * 3;
#pragma unroll
        for (int v = 0; v < 3; ++v) {
            float ssum = 0.0f, acc = 0.0f;
#pragma unroll
            for (int k = 0; k < 9; ++k) {
                const int j = k * 3 + v;
                const u32 w = mw[j >> 1];
                const float lg = (j & 1) ? __uint_as_float(w & 0xffff0000u)
                                         : __uint_as_float(w << 16);
                const float e = __builtin_amdgcn_exp2f(lg);
                ssum += e;
                acc = fmaf(xv[k], e, acc);
            }
            out[ob + v] = acc * __builtin_amdgcn_rcpf(ssum);
        }

        lds_fence();   // readback -> next iteration's init writes

        tb = tn;
#pragma unroll
        for (int k = 0; k < 9; ++k) xv[k] = xn[k];
    }
}

extern "C" void kernel_launch(void* const* d_in, const int* in_sizes, int n_in,
                              void* d_out, int out_size, void* d_ws, size_t ws_size,
                              hipStream_t stream) {
    // setup_inputs order: x, target_h, target_w, w1, b1, alpha, w2, b2
    const float* x     = (const float*)d_in[0];
    const float* w1    = (const float*)d_in[3];
    const float* b1    = (const float*)d_in[4];
    const float* alpha = (const float*)d_in[5];
    const float* w2    = (const float*)d_in[6];
    const float* b2    = (const float*)d_in[7];
    float* out = (float*)d_out;
    __hip_bfloat16* ws = (__hip_bfloat16*)d_ws;   // 3072 bf16 = 6 KB

    hipLaunchKernelGGL(prep_B, dim3(12), dim3(256), 0, stream, w1, b1, alpha, w2, b2, ws);
    hipLaunchKernelGGL(convex_upsample_mfma14, dim3(NBLK), dim3(256), 0, stream,
                       x, ws, out);
}

// Round 19
// 68.908 us; speedup vs baseline: 1.6875x; 1.6776x over previous
//
#include <hip/hip_runtime.h>
#include <hip/hip_bf16.h>

// ConvexWidthUpsampler R19: R18 (bf16-logit 80B rows, 7 blocks/CU by LDS)
// with the register cap fixed: __launch_bounds__(256,5) -> VGPR cap 102,
// compiler uses ~52 spill-free (R18's (256,7) forced VGPR=36 -> scratch
// spills, +90MB HBM traffic). Occupancy is LDS-limited at 7 blocks/CU.
//  - row = 80 B (5x16B): stride 20 banks mod 32, period-8 self-rotation
//  - logits bf16 (cvt_pk packed): scatter ds_write_b64, readback 4x b128
//  - NBLK 1792 = 7 x 256 (single resident cohort)
// Weak memory-clobber fences, z in registers (permuted-M2), scalar stores.
// B=16,C=1,H=512,W=512,up=(1,3). Output [16,1,512,1536] f32.

#define BB 16
#define HH 512
#define WW 512
#define HID 32
#define NM 27
#define LOG2E 1.44269504088896340736f
#define NT 16384
#define NBLK 1792
#define ROWB 80
#define ZOFF (64 * ROWB)   // 5120: per-wave broadcast-zero block

typedef short bf16x8 __attribute__((ext_vector_type(8)));
typedef float f32x4  __attribute__((ext_vector_type(4)));
typedef unsigned int u32;
typedef u32 u32x4 __attribute__((ext_vector_type(4)));
typedef u32 u32x2 __attribute__((ext_vector_type(2)));

__device__ __forceinline__ u32 pk2(float a, float b) {
    union { __hip_bfloat162 h2; u32 u; } cv;
    cv.h2 = __float22bfloat162_rn(make_float2(a, b));
    return cv.u;
}

// Compiler memory fence: forbids CSE/reordering of LDS ops across stages
// (TBAA guard for type-punned same-address accesses, the R5 bug class).
// No sched_barrier: VALU/MFMA float freely for latency hiding.
__device__ __forceinline__ void lds_fence() {
    asm volatile("" ::: "memory");
}

// 3x3 load with wave-uniform row logic (R15-proven): block covers half of
// one image row, so hrow/bidx/row-masks are scalar.
__device__ __forceinline__ void load_xv(const float* __restrict__ x, int tile,
                                        int tid, float xv[9]) {
    const int wcol = (tile & 1) * 256 + tid;       // lane-varying
    const int hrow = (tile >> 1) & (HH - 1);       // scalar
    const int bidx = tile >> 10;                   // scalar
    const float* xb = x + (size_t)bidx * (HH * WW);
    int wx[3]; bool wok[3];
#pragma unroll
    for (int i = 0; i < 3; ++i) {
        const int w = wcol + i - 1;
        wok[i] = (unsigned)w < (unsigned)WW;
        wx[i]  = w < 0 ? 0 : (w > WW - 1 ? WW - 1 : w);
    }
#pragma unroll
    for (int ki = 0; ki < 3; ++ki) {
        const int h = hrow + ki - 1;                       // scalar
        const bool hok = (unsigned)h < (unsigned)HH;       // scalar
        const int hy = h < 0 ? 0 : (h > HH - 1 ? HH - 1 : h);
        const float* rowp = xb + hy * WW;                  // scalar base
#pragma unroll
        for (int kj = 0; kj < 3; ++kj) {
            const float v = rowp[wx[kj]];
            xv[ki * 3 + kj] = (hok && wok[kj]) ? v : 0.0f;
        }
    }
}

// ws bf16 layout (hi-only, 3072 elems = 6 KB):
//   [0   ..1023] B2_32 [32 n][32 k]: k<9 M1[n][k], k==9 bias'[n], else 0 (xlog2e)
//   [1024..2047] M2p   [32 n][32 k]: M2[n][pi(k)] (xlog2e), n>=27 -> 0
//   [2048..3071] B1    [32 n][32 k]: k<9 w1[n][k], k==9 b1[n], else 0
__global__ void prep_B(const float* __restrict__ w1, const float* __restrict__ b1,
                       const float* __restrict__ alpha, const float* __restrict__ w2,
                       const float* __restrict__ b2, __hip_bfloat16* __restrict__ ws) {
    const int i = blockIdx.x * 256 + threadIdx.x;
    if (i >= 3072) return;
    const int sec = i >> 10;
    const int r   = i & 1023;
    const int n   = r >> 5, k = r & 31;
    float v = 0.0f;
    if (sec == 0) {
        if (n < NM) {
            if (k < 9) {
                for (int c = 0; c < HID; ++c)
                    v += w2[n * HID + c] * (0.5f * (1.0f + alpha[c])) * w1[c * 9 + k];
            } else if (k == 9) {
                v = b2[n];
                for (int c = 0; c < HID; ++c)
                    v += w2[n * HID + c] * (0.5f * (1.0f + alpha[c])) * b1[c];
            }
        }
        v *= LOG2E;
    } else if (sec == 1) {
        if (n < NM) {
            const int c = ((k & 4) ? 16 : 0) + (k >> 3) * 4 + (k & 3);  // pi(k)
            v = w2[n * HID + c] * (0.5f * (1.0f - alpha[c])) * LOG2E;
        }
    } else {
        v = (k < 9) ? w1[n * 9 + k] : (k == 9 ? b1[n] : 0.0f);
    }
    ws[i] = __float2bfloat16(v);
}

__global__ __launch_bounds__(256, 5) void convex_upsample_mfma15(
    const float* __restrict__ x,            // [16,1,512,512]
    const __hip_bfloat16* __restrict__ ws,  // prep output
    float* __restrict__ out)                // [16,1,512,1536]
{
    __shared__ char lds_raw[4][ZOFF + 16];  // 4 x 5136 = 20544 B -> 7 blocks/CU

    const int tid  = threadIdx.x;
    const int wv   = tid >> 6;
    const int lane = tid & 63;
    const int l16  = lane & 15;
    const int lq   = lane >> 4;
    char* wbase = lds_raw[wv];

    // persistent weight fragments (hi only): lane row n = nt*16+l16, k = lq*8+i
    bf16x8 Bf2[2], M2p[2], Bf1[2];
#pragma unroll
    for (int nt = 0; nt < 2; ++nt) {
        const int ro = (nt * 16 + l16) * 32 + lq * 8;
        Bf2[nt] = *(const bf16x8*)(ws + ro);
        M2p[nt] = *(const bf16x8*)(ws + 1024 + ro);
        Bf1[nt] = *(const bf16x8*)(ws + 2048 + ro);
    }

    // broadcast-zero block (idempotent per-wave write; read by lq>=2 a0 loads)
    *(u32x4*)(wbase + ZOFF) = (u32x4){0u, 0u, 0u, 0u};

    int tb = blockIdx.x;
    float xv[9];
    load_xv(x, tb, tid, xv);

    while (tb < NT) {
        const int tn  = tb + NBLK;
        const int tpf = (tn < NT) ? tn : 0;
        float xn[9];
        load_xv(x, tpf, tid, xn);   // prefetch next tile during this compute

        // ---- init my row bytes 0..31: k0..8=xv, k9=1, k10..15=0 ----
        char* myrow = wbase + lane * ROWB;
        *(u32x4*)(myrow)      = (u32x4){pk2(xv[0], xv[1]), pk2(xv[2], xv[3]),
                                        pk2(xv[4], xv[5]), pk2(xv[6], xv[7])};
        *(u32x4*)(myrow + 16) = (u32x4){pk2(xv[8], 1.0f), 0u, 0u, 0u};

        lds_fence();   // init writes -> cross-lane a0 reads

        // ---- hoisted a0 reads; lq>=2 lanes read the broadcast-zero block ----
        bf16x8 a0[4];
#pragma unroll
        for (int mt = 0; mt < 4; ++mt) {
            const char* ab = wbase + (mt * 16 + l16) * ROWB;
            const char* aptr = (lq < 2) ? (ab + lq * 16) : (wbase + ZOFF);
            a0[mt] = *(const bf16x8*)aptr;
        }

        lds_fence();   // a0 reads -> scatters below (TBAA/reorder guard)

        // ---- per mt: z in-register -> logits -> bf16 scatter ----
#pragma unroll
        for (int mt = 0; mt < 4; ++mt) {
            char* ab = wbase + (mt * 16 + l16) * ROWB;
            // round 1: z[ch][px]; lane(l16,lq) gets ch = {lq*4+r, 16+lq*4+r}, px = l16
            f32x4 z0 = {0.f, 0.f, 0.f, 0.f}, z1 = {0.f, 0.f, 0.f, 0.f};
            z0 = __builtin_amdgcn_mfma_f32_16x16x32_bf16(Bf1[0], a0[mt], z0, 0, 0, 0);
            z1 = __builtin_amdgcn_mfma_f32_16x16x32_bf16(Bf1[1], a0[mt], z1, 0, 0, 0);
            // pack |z| as permuted B-operand fragment (k = lq*8+i -> ch pi(k))
            union { u32 u[4]; bf16x8 h; } zf;
            zf.u[0] = pk2(fabsf(z0[0]), fabsf(z0[1]));
            zf.u[1] = pk2(fabsf(z0[2]), fabsf(z0[3]));
            zf.u[2] = pk2(fabsf(z1[0]), fabsf(z1[1]));
            zf.u[3] = pk2(fabsf(z1[2]), fabsf(z1[3]));
            // round 2: logits m[n][px] = M2p*|z| + B2*a0
            f32x4 c0 = {0.f, 0.f, 0.f, 0.f}, c1 = {0.f, 0.f, 0.f, 0.f};
            c0 = __builtin_amdgcn_mfma_f32_16x16x32_bf16(M2p[0], zf.h,   c0, 0, 0, 0);
            c0 = __builtin_amdgcn_mfma_f32_16x16x32_bf16(Bf2[0], a0[mt], c0, 0, 0, 0);
            c1 = __builtin_amdgcn_mfma_f32_16x16x32_bf16(M2p[1], zf.h,   c1, 0, 0, 0);
            c1 = __builtin_amdgcn_mfma_f32_16x16x32_bf16(Bf2[1], a0[mt], c1, 0, 0, 0);
            // bf16 scatter for pixel mt*16+l16 (logit n at byte 2n):
            //   c0: n = lq*4..+3     -> bytes 8*lq      (0..31)
            //   c1: n = 16+lq*4..+3  -> bytes 32 + 8*lq (32..55), lq==3 dropped
            *(u32x2*)(ab + 8 * lq) = (u32x2){pk2(c0[0], c0[1]), pk2(c0[2], c0[3])};
            if (lq < 3)
                *(u32x2*)(ab + 32 + 8 * lq) = (u32x2){pk2(c1[0], c1[1]), pk2(c1[2], c1[3])};
        }

        lds_fence();   // scatters -> readback

        // ---- readback 27 bf16 logits (bytes 0..53) as 16 u32 words ----
        u32 mw[16];
#pragma unroll
        for (int q = 0; q < 4; ++q) {
            const u32x4 t = *(const u32x4*)(myrow + q * 16);
            mw[4 * q + 0] = t[0]; mw[4 * q + 1] = t[1];
            mw[4 * q + 2] = t[2]; mw[4 * q + 3] = t[3];
        }

        // ---- softmax (base-2, pre-scaled, no max-sub) + combine + store ----
        const int p = tb * 256 + tid;
        const size_t ob = (size_t)p * 3;
#pragma unroll
        for (int v = 0; v < 3; ++v) {
            float ssum = 0.0f, acc = 0.0f;
#pragma unroll
            for (int k = 0; k < 9; ++k) {
                const int j = k * 3 + v;
                const u32 w = mw[j >> 1];
                const float lg = (j & 1) ? __uint_as_float(w & 0xffff0000u)
                                         : __uint_as_float(w << 16);
                const float e = __builtin_amdgcn_exp2f(lg);
                ssum += e;
                acc = fmaf(xv[k], e, acc);
            }
            out[ob + v] = acc * __builtin_amdgcn_rcpf(ssum);
        }

        lds_fence();   // readback -> next iteration's init writes

        tb = tn;
#pragma unroll
        for (int k = 0; k < 9; ++k) xv[k] = xn[k];
    }
}

extern "C" void kernel_launch(void* const* d_in, const int* in_sizes, int n_in,
                              void* d_out, int out_size, void* d_ws, size_t ws_size,
                              hipStream_t stream) {
    // setup_inputs order: x, target_h, target_w, w1, b1, alpha, w2, b2
    const float* x     = (const float*)d_in[0];
    const float* w1    = (const float*)d_in[3];
    const float* b1    = (const float*)d_in[4];
    const float* alpha = (const float*)d_in[5];
    const float* w2    = (const float*)d_in[6];
    const float* b2    = (const float*)d_in[7];
    float* out = (float*)d_out;
    __hip_bfloat16* ws = (__hip_bfloat16*)d_ws;   // 3072 bf16 = 6 KB

    hipLaunchKernelGGL(prep_B, dim3(12), dim3(256), 0, stream, w1, b1, alpha, w2, b2, ws);
    hipLaunchKernelGGL(convex_upsample_mfma15, dim3(NBLK), dim3(256), 0, stream,
                       x, ws, out);
}

// Round 20
// 58.088 us; speedup vs baseline: 2.0019x; 1.1863x over previous
//
#include <hip/hip_runtime.h>
#include <hip/hip_bf16.h>

// ConvexWidthUpsampler R20: 32x32x16 MFMA, softmax in the D-fragment domain.
// Per wave (64 px): 2 fragments of 32 px. Round 1: z = mfma(B1, a) (1 MFMA,
// K=16 holds xv,1,zeros). Packed |z| re-enters as B-operand under channel map
// ch(k) = (k&3)+8((k>>2)&1)+4(k>>3) (M2 columns pre-permuted in prep, lo/hi).
// Round 2: m = mfma(B2a,a) + mfma(M2pL,zfL) + mfma(M2pH,zfH). Mask-matrix
// OUTPUT rows are pre-permuted so D-reg r maps to (k,v) = (r/3, r%3) [lo=0]
// or (5+r/3, r%3) [lo=1] -- softmax fully in registers, compile-time indexed.
// Garbage rows n>=27: prep writes bias=-100 -> exp2 -> 0 (free masking).
// x exchanged across the xor-32 pair (9 shfl); pixel sums finished with
// 6 shfl_xor(32)+add; every lane stores its own pixel (lane id).
// DS ops/tile: 4 (2 init writes + 2 a-reads). LDS 12288 B/block.
// B=16,C=1,H=512,W=512,up=(1,3). Output [16,1,512,1536] f32.

#define BB 16
#define HH 512
#define WW 512
#define HID 32
#define NM 27
#define LOG2E 1.44269504088896340736f
#define NT 16384
#define NBLK 2048
#define ROWB 48   // 3x16B: stride-3 block rotation -> conflict-free reads

typedef short bf16x8 __attribute__((ext_vector_type(8)));
typedef float f32x16 __attribute__((ext_vector_type(16)));
typedef unsigned int u32;
typedef u32 u32x4 __attribute__((ext_vector_type(4)));

#define ZERO16 (f32x16){0.f,0.f,0.f,0.f,0.f,0.f,0.f,0.f,0.f,0.f,0.f,0.f,0.f,0.f,0.f,0.f}

__device__ __forceinline__ u32 pk2(float a, float b) {
    union { __hip_bfloat162 h2; u32 u; } cv;
    cv.h2 = __float22bfloat162_rn(make_float2(a, b));
    return cv.u;
}

// Compiler memory fence (R15-proven): orders LDS ops across stages, no
// sched_barrier so VALU/MFMA schedule freely.
__device__ __forceinline__ void lds_fence() {
    asm volatile("" ::: "memory");
}

// 3x3 load with wave-uniform row logic (R15-proven).
__device__ __forceinline__ void load_xv(const float* __restrict__ x, int tile,
                                        int tid, float xv[9]) {
    const int wcol = (tile & 1) * 256 + tid;
    const int hrow = (tile >> 1) & (HH - 1);
    const int bidx = tile >> 10;
    const float* xb = x + (size_t)bidx * (HH * WW);
    int wx[3]; bool wok[3];
#pragma unroll
    for (int i = 0; i < 3; ++i) {
        const int w = wcol + i - 1;
        wok[i] = (unsigned)w < (unsigned)WW;
        wx[i]  = w < 0 ? 0 : (w > WW - 1 ? WW - 1 : w);
    }
#pragma unroll
    for (int ki = 0; ki < 3; ++ki) {
        const int h = hrow + ki - 1;
        const bool hok = (unsigned)h < (unsigned)HH;
        const int hy = h < 0 ? 0 : (h > HH - 1 ? HH - 1 : h);
        const float* rowp = xb + hy * WW;
#pragma unroll
        for (int kj = 0; kj < 3; ++kj) {
            const float v = rowp[wx[kj]];
            xv[ki * 3 + kj] = (hok && wok[kj]) ? v : 0.0f;
        }
    }
}

// ws bf16 layout, 4 sections x [32 n][16 c] = 2048 elems (4 KB):
//  S0 B2a : row n -> logit j via (lo,r) inversion; c<9 M1[j][c]*L2E,
//           c==9 bias'[j]*L2E (invalid rows: -100 mask), else 0
//  S1 M2pL: M2[j][ch(c)]*L2E          S2 M2pH: M2[j][16+ch(c)]*L2E
//  S3 B1  : c<9 w1[n][c], c==9 b1[n], else 0   (n = hidden channel)
// where lo=(n>>2)&1, r=(n&3)+4*(n>>3); valid iff (lo==0&&r<15)||(lo==1&&r<12);
// k = lo==0 ? r/3 : 5+r/3; v = r%3; j = 3k+v; ch(c)=(c&3)+8((c>>2)&1)+4(c>>3).
__global__ void prep_B(const float* __restrict__ w1, const float* __restrict__ b1,
                       const float* __restrict__ alpha, const float* __restrict__ w2,
                       const float* __restrict__ b2, __hip_bfloat16* __restrict__ ws) {
    const int i = blockIdx.x * 256 + threadIdx.x;
    if (i >= 2048) return;
    const int sec = i >> 9;
    const int rr  = i & 511;
    const int n   = rr >> 4, c = rr & 15;
    const int lo  = (n >> 2) & 1;
    const int r   = (n & 3) + 4 * (n >> 3);
    const bool valid = lo == 0 ? (r < 15) : (r < 12);
    const int k = (lo == 0) ? (r / 3) : (5 + r / 3);
    const int j = 3 * k + (r % 3);
    const int ch = (c & 3) + 8 * ((c >> 2) & 1) + 4 * (c >> 3);
    float v = 0.0f;
    if (sec == 0) {
        if (valid) {
            if (c < 9) {
                for (int q = 0; q < HID; ++q)
                    v += w2[j * HID + q] * (0.5f * (1.0f + alpha[q])) * w1[q * 9 + c];
                v *= LOG2E;
            } else if (c == 9) {
                v = b2[j];
                for (int q = 0; q < HID; ++q)
                    v += w2[j * HID + q] * (0.5f * (1.0f + alpha[q])) * b1[q];
                v *= LOG2E;
            }
        } else if (c == 9) {
            v = -100.0f;   // mask row: logit=-100 -> exp2 ~ 0
        }
    } else if (sec == 1) {
        if (valid) v = w2[j * HID + ch] * (0.5f * (1.0f - alpha[ch])) * LOG2E;
    } else if (sec == 2) {
        if (valid) v = w2[j * HID + 16 + ch] * (0.5f * (1.0f - alpha[16 + ch])) * LOG2E;
    } else {
        v = (c < 9) ? w1[n * 9 + c] : (c == 9 ? b1[n] : 0.0f);
    }
    ws[i] = __float2bfloat16(v);
}

__global__ __launch_bounds__(256, 4) void convex_upsample_w32(
    const float* __restrict__ x,            // [16,1,512,512]
    const __hip_bfloat16* __restrict__ ws,  // prep output
    float* __restrict__ out)                // [16,1,512,1536]
{
    __shared__ char lds_raw[4][64 * ROWB];  // 12288 B/block

    const int tid  = threadIdx.x;
    const int wv   = tid >> 6;
    const int lane = tid & 63;
    const int l32  = lane & 31;
    const int lo   = lane >> 5;
    char* wbase = lds_raw[wv];

    // persistent weight fragments: A-operand row = l32, k = lo*8 + i
    const int widx = l32 * 16 + lo * 8;
    const bf16x8 B2a  = *(const bf16x8*)(ws + widx);
    const bf16x8 M2pL = *(const bf16x8*)(ws + 512 + widx);
    const bf16x8 M2pH = *(const bf16x8*)(ws + 1024 + widx);
    const bf16x8 B1f  = *(const bf16x8*)(ws + 1536 + widx);

    int tb = blockIdx.x;
    float xv[9];
    load_xv(x, tb, tid, xv);

    while (tb < NT) {
        const int tn  = tb + NBLK;
        const int tpf = (tn < NT) ? tn : 0;
        float xn[9];
        load_xv(x, tpf, tid, xn);   // prefetch next tile

        // ---- init my row (32 B): k0..8=xv, k9=1, k10..15=0 ----
        char* myrow = wbase + lane * ROWB;
        *(u32x4*)(myrow)      = (u32x4){pk2(xv[0], xv[1]), pk2(xv[2], xv[3]),
                                        pk2(xv[4], xv[5]), pk2(xv[6], xv[7])};
        *(u32x4*)(myrow + 16) = (u32x4){pk2(xv[8], 1.0f), 0u, 0u, 0u};

        lds_fence();   // init writes -> cross-lane a reads

        // ---- the only LDS reads: B-operand fragments (col=l32, k=lo*8+i) ----
        const bf16x8 aA = *(const bf16x8*)(wbase + l32 * ROWB + lo * 16);
        const bf16x8 aB = *(const bf16x8*)(wbase + (32 + l32) * ROWB + lo * 16);

        lds_fence();   // a reads -> (next iteration's) init writes

        // ---- x exchange across xor-32 pair + per-fragment x selects ----
        float xsh[9];
#pragma unroll
        for (int i = 0; i < 9; ++i) xsh[i] = __shfl_xor(xv[i], 32, 64);
        float xsel[2][5];
#pragma unroll
        for (int i = 0; i < 4; ++i) {
            xsel[0][i] = lo ? xsh[5 + i] : xv[i];    // frag A (pixel l32)
            xsel[1][i] = lo ? xv[5 + i] : xsh[i];    // frag B (pixel 32+l32)
        }
        xsel[0][4] = lo ? 0.0f : xv[4];
        xsel[1][4] = lo ? 0.0f : xsh[4];

        float num[2][3], den[2][3];
#pragma unroll
        for (int f = 0; f < 2; ++f) {
            const bf16x8 a = f ? aB : aA;
            // round 1: z[ch][px] = B1 * a   (1 MFMA, all 32 hidden channels)
            f32x16 zz = ZERO16;
            zz = __builtin_amdgcn_mfma_f32_32x32x16_bf16(B1f, a, zz, 0, 0, 0);
            // pack |z| -> two B-operands (channel map ch(k), baked into M2pL/H)
            union { u32 u[8]; bf16x8 h[2]; } zf;
#pragma unroll
            for (int i = 0; i < 8; ++i)
                zf.u[i] = pk2(fabsf(zz[2 * i]), fabsf(zz[2 * i + 1]));
            // round 2: logits (output rows pre-permuted for (r/3, r%3) mapping)
            f32x16 m = ZERO16;
            m = __builtin_amdgcn_mfma_f32_32x32x16_bf16(B2a,  a,       m, 0, 0, 0);
            m = __builtin_amdgcn_mfma_f32_32x32x16_bf16(M2pL, zf.h[0], m, 0, 0, 0);
            m = __builtin_amdgcn_mfma_f32_32x32x16_bf16(M2pH, zf.h[1], m, 0, 0, 0);
            // in-register softmax partials: reg r -> (k = r/3 [+5 if lo], v = r%3)
            float nu[3] = {0.f, 0.f, 0.f}, de[3] = {0.f, 0.f, 0.f};
#pragma unroll
            for (int r = 0; r < 15; ++r) {
                const float e = __builtin_amdgcn_exp2f(m[r]);
                de[r % 3] += e;
                nu[r % 3] = fmaf(xsel[f][r / 3], e, nu[r % 3]);
            }
#pragma unroll
            for (int v = 0; v < 3; ++v) { num[f][v] = nu[v]; den[f][v] = de[v]; }
        }

        // ---- finish per-pixel sums across the xor-32 pair ----
#pragma unroll
        for (int f = 0; f < 2; ++f)
#pragma unroll
            for (int v = 0; v < 3; ++v) {
                num[f][v] += __shfl_xor(num[f][v], 32, 64);
                den[f][v] += __shfl_xor(den[f][v], 32, 64);
            }

        // ---- every lane stores its own pixel (lo selects its fragment) ----
        const size_t ob = (size_t)(tb * 256 + tid) * 3;
#pragma unroll
        for (int v = 0; v < 3; ++v) {
            const float nn = lo ? num[1][v] : num[0][v];
            const float dd = lo ? den[1][v] : den[0][v];
            out[ob + v] = nn * __builtin_amdgcn_rcpf(dd);
        }

        tb = tn;
#pragma unroll
        for (int k = 0; k < 9; ++k) xv[k] = xn[k];
    }
}

extern "C" void kernel_launch(void* const* d_in, const int* in_sizes, int n_in,
                              void* d_out, int out_size, void* d_ws, size_t ws_size,
                              hipStream_t stream) {
    // setup_inputs order: x, target_h, target_w, w1, b1, alpha, w2, b2
    const float* x     = (const float*)d_in[0];
    const float* w1    = (const float*)d_in[3];
    const float* b1    = (const float*)d_in[4];
    const float* alpha = (const float*)d_in[5];
    const float* w2    = (const float*)d_in[6];
    const float* b2    = (const float*)d_in[7];
    float* out = (float*)d_out;
    __hip_bfloat16* ws = (__hip_bfloat16*)d_ws;   // 2048 bf16 = 4 KB

    hipLaunchKernelGGL(prep_B, dim3(8), dim3(256), 0, stream, w1, b1, alpha, w2, b2, ws);
    hipLaunchKernelGGL(convex_upsample_w32, dim3(NBLK), dim3(256), 0, stream,
                       x, ws, out);
}